// Round 3
// 540.420 us; speedup vs baseline: 1.1404x; 1.1404x over previous
//
#include <hip/hip_runtime.h>
#include <stdint.h>

typedef __attribute__((ext_vector_type(8))) short bf16x8;
typedef __attribute__((ext_vector_type(4))) short bf16x4;
typedef __attribute__((ext_vector_type(4))) float f32x4;
typedef __attribute__((ext_vector_type(4))) unsigned short u16x4;

#define DIM   4096
#define SEQ   2048
#define NH    32
#define NKV   8
#define HD    128
#define QKV_N 6144  /* 4096 q + 1024 k + 1024 v */
#define ATT_SCALE 0.08838834764831845f /* 1/sqrt(128) */

static __device__ __forceinline__ unsigned short f2bf_bits(float f) {
  uint32_t x = __builtin_bit_cast(uint32_t, f);
  x += 0x7fffu + ((x >> 16) & 1u);   // RNE; inputs finite
  return (unsigned short)(x >> 16);
}
static __device__ __forceinline__ float bf_bits2f(unsigned short u) {
  uint32_t x = ((uint32_t)u) << 16;
  return __builtin_bit_cast(float, x);
}

// async global->LDS, 16B per lane (global_load_lds_dwordx4).
// LDS dest must be wave-contiguous: base + lane*16.
static __device__ __forceinline__ void g2l16(const unsigned short* gp,
                                             unsigned short* lp) {
  __builtin_amdgcn_global_load_lds(
      (const __attribute__((address_space(1))) unsigned int*)gp,
      (__attribute__((address_space(3))) unsigned int*)lp, 16, 0, 0);
}

// ---------------------------------------------------------------------------
// fp32 (R x C) -> bf16 (C x R), 32x32 tiles via LDS.
// ---------------------------------------------------------------------------
__global__ __launch_bounds__(256) void transpose_f32_bf16(
    const float* __restrict__ in, unsigned short* __restrict__ out,
    int ld_in, int ld_out) {
  __shared__ unsigned short sh[32][33];
  const int c0 = blockIdx.x * 32, r0 = blockIdx.y * 32;
  const int t = threadIdx.x;
  const int cc = t & 31, rr = (t >> 5) * 4;
#pragma unroll
  for (int p = 0; p < 4; ++p)
    sh[cc][rr + p] = f2bf_bits(in[(size_t)(r0 + rr + p) * ld_in + (c0 + cc)]);
  __syncthreads();
#pragma unroll
  for (int p = 0; p < 4; ++p)
    out[(size_t)(c0 + rr + p) * ld_out + (r0 + cc)] = sh[rr + p][cc];
}

// bf16 (R x C) -> bf16 (C x R)
__global__ __launch_bounds__(256) void transpose_bf16(
    const unsigned short* __restrict__ in, unsigned short* __restrict__ out,
    int ld_in, int ld_out) {
  __shared__ unsigned short sh[32][33];
  const int c0 = blockIdx.x * 32, r0 = blockIdx.y * 32;
  const int t = threadIdx.x;
  const int cc = t & 31, rr = (t >> 5) * 4;
#pragma unroll
  for (int p = 0; p < 4; ++p)
    sh[cc][rr + p] = in[(size_t)(r0 + rr + p) * ld_in + (c0 + cc)];
  __syncthreads();
#pragma unroll
  for (int p = 0; p < 4; ++p)
    out[(size_t)(c0 + rr + p) * ld_out + (r0 + cc)] = sh[rr + p][cc];
}

// fp32 -> bf16 elementwise (x pre-conversion), 4 elems/thread
__global__ __launch_bounds__(256) void convert_f32_bf16(
    const float* __restrict__ in, unsigned short* __restrict__ out) {
  const int i = (blockIdx.x * 256 + threadIdx.x) * 4;
  const float4 v = *(const float4*)&in[i];
  u16x4 w;
  w[0] = f2bf_bits(v.x); w[1] = f2bf_bits(v.y);
  w[2] = f2bf_bits(v.z); w[3] = f2bf_bits(v.w);
  *(u16x4*)&out[i] = w;
}

// ---------------------------------------------------------------------------
// C(M,N) = A(M,K) @ Bt(N,K)^T.  bf16 in; C fp32 or bf16. 128x128, BK=32.
// m97 structure: linear LDS [128][32] + global_load_lds width 16.
// ---------------------------------------------------------------------------
#define BM 128
#define BN 128
#define BK 32

template <bool OUT_FP32>
__global__ __launch_bounds__(256) void gemm_bt(
    const unsigned short* __restrict__ A, int lda,
    const unsigned short* __restrict__ Bt, int ldb,
    void* __restrict__ C_, int ldc, int K) {
  __shared__ __align__(16) unsigned short ldsA[BM * BK];  // 8 KB, linear
  __shared__ __align__(16) unsigned short ldsB[BN * BK];  // 8 KB, linear
  const int t = threadIdx.x;
  const int wave = t >> 6, lane = t & 63;
  const int lane16 = lane & 15, quad = lane >> 4;
  const int m0 = blockIdx.y * BM, n0 = blockIdx.x * BN;
  const int wrow = (wave >> 1) * 64, wcol = (wave & 1) * 64;

  f32x4 acc[4][4];
#pragma unroll
  for (int i = 0; i < 4; ++i)
#pragma unroll
    for (int j = 0; j < 4; ++j) acc[i][j] = (f32x4){0.f, 0.f, 0.f, 0.f};

  // staging: thread t loads 16B; row = t>>2 (64 rows/pass), col = (t&3)*8.
  // LDS dst = t*8 shorts == wave_base + lane*16B (wave-contiguous, linear).
  const int srow = t >> 2;
  const int scol = (t & 3) * 8;
  const size_t arow0 = (size_t)(m0 + srow) * lda;
  const size_t arow1 = (size_t)(m0 + 64 + srow) * lda;
  const size_t brow0 = (size_t)(n0 + srow) * ldb;
  const size_t brow1 = (size_t)(n0 + 64 + srow) * ldb;

  for (int kk = 0; kk < K; kk += BK) {
    __syncthreads();
    g2l16(&A[arow0 + kk + scol],  &ldsA[t * 8]);
    g2l16(&A[arow1 + kk + scol],  &ldsA[2048 + t * 8]);
    g2l16(&Bt[brow0 + kk + scol], &ldsB[t * 8]);
    g2l16(&Bt[brow1 + kk + scol], &ldsB[2048 + t * 8]);
    __syncthreads();   // compiler drains vmcnt(0) before s_barrier

    bf16x8 af[4], bfr[4];
#pragma unroll
    for (int mi = 0; mi < 4; ++mi)
      af[mi] = *(const bf16x8*)&ldsA[(wrow + mi * 16 + lane16) * BK + quad * 8];
#pragma unroll
    for (int ni = 0; ni < 4; ++ni)
      bfr[ni] = *(const bf16x8*)&ldsB[(wcol + ni * 16 + lane16) * BK + quad * 8];
#pragma unroll
    for (int mi = 0; mi < 4; ++mi)
#pragma unroll
      for (int ni = 0; ni < 4; ++ni)
        acc[mi][ni] = __builtin_amdgcn_mfma_f32_16x16x32_bf16(
            af[mi], bfr[ni], acc[mi][ni], 0, 0, 0);
  }

#pragma unroll
  for (int mi = 0; mi < 4; ++mi)
#pragma unroll
    for (int ni = 0; ni < 4; ++ni)
#pragma unroll
      for (int r = 0; r < 4; ++r) {
        const int row = m0 + wrow + mi * 16 + quad * 4 + r;
        const int col = n0 + wcol + ni * 16 + lane16;
        if (OUT_FP32)
          ((float*)C_)[(size_t)row * ldc + col] = acc[mi][ni][r];
        else
          ((unsigned short*)C_)[(size_t)row * ldc + col] = f2bf_bits(acc[mi][ni][r]);
      }
}

// ---------------------------------------------------------------------------
// Interleaved RoPE in place on qkv.
// ---------------------------------------------------------------------------
__global__ __launch_bounds__(256) void rope_kernel(unsigned short* __restrict__ qkv) {
  const int idx = blockIdx.x * 256 + threadIdx.x;
  const int pos = idx / 2560;
  const int rem = idx - pos * 2560;
  const int head = rem >> 6;
  const int i = rem & 63;
  const float inv_freq = __expf(-(float)(2 * i) * (9.210340371976184f / 128.0f));
  const float ang = (float)pos * inv_freq;
  float s, c;
  __sincosf(ang, &s, &c);
  const int col = (head < 32) ? head * 128 + 2 * i
                              : 4096 + (head - 32) * 128 + 2 * i;
  unsigned short* p = qkv + (size_t)pos * QKV_N + col;
  const float tr = bf_bits2f(p[0]), ti = bf_bits2f(p[1]);
  p[0] = f2bf_bits(tr * c - ti * s);
  p[1] = f2bf_bits(tr * s + ti * c);
}

// ---------------------------------------------------------------------------
// Flash attention, operand-swapped (S^T = K@Q^T; PV via K=16 MFMA).
// Causal-pairing load balance: block b -> q-tiles {31-b, b} = 33 iters each.
// New this round:
//  - T14 async-STAGE: prefetch next K/V tile into regs, hide under compute;
//    barrier B is raw s_barrier + lgkmcnt(0) so vmcnt is NOT drained.
//  - V LDS: [128][64] with 8B-unit XOR swizzle (unit ^= (row&7)<<1) --
//    fixes even-banks-only 2x conflict of the old padded layout.
//  - T13 defer-max: skip m-update + o-rescale when __all(mx <= m + 8).
//  - T5 setprio(1) around MFMA clusters.
// ---------------------------------------------------------------------------
#define QT 64
#define KT 64
#define KLS (HD + 8)   /* 136 shorts, 272 B rows: balanced banks for b128 reads */
#define NQ  (SEQ / QT) /* 32 q-tiles */
#define DEFER_THR 8.0f

__global__ __launch_bounds__(256) void attn_kernel(
    const unsigned short* __restrict__ qkv,
    const unsigned short* __restrict__ vT,
    unsigned short* __restrict__ attn) {
  __shared__ __align__(16) unsigned short kls[KT][KLS];   // 17408 B
  __shared__ __align__(16) unsigned short vls[HD][KT];    // 16384 B, swizzled

  const int t = threadIdx.x;
  const int wave = t >> 6, lane = t & 63;
  const int lane16 = lane & 15, quad = lane >> 4;
  const int h = blockIdx.y, kvh = h >> 2;
  const unsigned short* kbase = qkv + 4096 + kvh * HD;
  const unsigned short* vbase = vT + (size_t)kvh * HD * SEQ;

  // staging geometry (fixed per thread)
  const int kr = t >> 2, kc = (t & 3) * 8;   // K tile: row, col base
  const int vd = t >> 1;                     // V^T dim row
  const int vu0 = (t & 1) * 8;               // V 8B-unit base (1 unit = 4 shorts)
  const int vswz = (vd & 7) << 1;            // XOR mask on 8B units (write side)
  const int rswz = (lane16 & 7) << 1;        // XOR mask on 8B units (read side)
  const unsigned short* ksrc0 = &kbase[(size_t)kr * QKV_N + kc];
  const unsigned short* vsrc0 = &vbase[(size_t)vd * SEQ + (t & 1) * 32];

  bf16x8 kreg[4], vreg[4];

  for (int half = 0; half < 2; ++half) {
    const int qt = half ? (int)blockIdx.x : (NQ - 1 - (int)blockIdx.x);
    const int q0 = qt * QT;
    const int wq0 = q0 + wave * 16;
    const int qrow = wq0 + lane16;                 // this lane's q row
    const int nkb = qt + 1;

    // prologue prefetch of tile kb=0 (registers only; LDS still owned by
    // previous half's compute until the first __syncthreads below)
#pragma unroll
    for (int j = 0; j < 4; ++j) kreg[j] = *(const bf16x8*)&ksrc0[j * 32];
#pragma unroll
    for (int j = 0; j < 4; ++j) vreg[j] = *(const bf16x8*)&vsrc0[j * 8];

    const unsigned short* qbase = qkv + (size_t)wq0 * QKV_N + h * HD;

    // Q fragments (B-operand): B[n=lane16][k=quad*8+j]
    bf16x8 qf[4];
#pragma unroll
    for (int dc = 0; dc < 4; ++dc)
      qf[dc] = *(const bf16x8*)&qbase[(size_t)lane16 * QKV_N + dc * 32 + quad * 8];

    f32x4 o[8];  // O^T[d][q] accumulators, d = dt*16 + (quad*4+reg)
#pragma unroll
    for (int i = 0; i < 8; ++i) o[i] = (f32x4){0.f, 0.f, 0.f, 0.f};
    float m = -INFINITY, l = 0.f;

    for (int kb = 0; kb < nkb; ++kb) {
      const int key0 = kb * KT;
      __syncthreads();   // all waves done reading LDS; drains prefetch vmcnt

      // store staged tile regs -> LDS
#pragma unroll
      for (int j = 0; j < 4; ++j)
        *(bf16x8*)&kls[kr][kc + j * 32] = kreg[j];
#pragma unroll
      for (int j = 0; j < 4; ++j)
        *(bf16x8*)&vls[vd][((vu0 + j * 2) ^ vswz) * 4] = vreg[j];

      // prefetch next tile (stays in flight across the raw barrier below)
      if (kb + 1 < nkb) {
        const unsigned short* ks = ksrc0 + (size_t)(kb + 1) * KT * QKV_N;
        const unsigned short* vs = vsrc0 + (kb + 1) * KT;
#pragma unroll
        for (int j = 0; j < 4; ++j) kreg[j] = *(const bf16x8*)&ks[j * 32];
#pragma unroll
        for (int j = 0; j < 4; ++j) vreg[j] = *(const bf16x8*)&vs[j * 8];
      }

      asm volatile("s_waitcnt lgkmcnt(0)" ::: "memory");  // ds_writes visible
      __builtin_amdgcn_s_barrier();                       // no vmcnt drain

      // S^T[s][q]: A=K (m=s), B=Q (n=q); 4 key sub-tiles
      f32x4 S[4];
      __builtin_amdgcn_s_setprio(1);
#pragma unroll
      for (int kt = 0; kt < 4; ++kt) {
        f32x4 sacc = (f32x4){0.f, 0.f, 0.f, 0.f};
#pragma unroll
        for (int dc = 0; dc < 4; ++dc) {
          const bf16x8 kf = *(const bf16x8*)&kls[kt * 16 + lane16][dc * 32 + quad * 8];
          sacc = __builtin_amdgcn_mfma_f32_16x16x32_bf16(kf, qf[dc], sacc, 0, 0, 0);
        }
        S[kt] = sacc;
      }
      __builtin_amdgcn_s_setprio(0);

      // per-lane softmax over this lane's 16 s-values, reduce across quads
      float sv[4][4], mx = -INFINITY;
#pragma unroll
      for (int kt = 0; kt < 4; ++kt)
#pragma unroll
        for (int r = 0; r < 4; ++r) {
          const int key = key0 + kt * 16 + quad * 4 + r;
          sv[kt][r] = (key <= qrow) ? S[kt][r] * ATT_SCALE : -INFINITY;
          mx = fmaxf(mx, sv[kt][r]);
        }
      mx = fmaxf(mx, __shfl_xor(mx, 16, 64));
      mx = fmaxf(mx, __shfl_xor(mx, 32, 64));

      // T13 defer-max: keep old m while growth <= THR (p bounded by e^THR)
      const bool skip = __all(mx <= m + DEFER_THR);
      float alpha = 1.f;
      if (!skip) {
        const float newm = fmaxf(m, mx);
        alpha = __expf(m - newm);   // 0 on first block
        m = newm;
      }
      float p[4][4], rs = 0.f;
#pragma unroll
      for (int kt = 0; kt < 4; ++kt)
#pragma unroll
        for (int r = 0; r < 4; ++r) {
          p[kt][r] = __expf(sv[kt][r] - m);  // exp(-inf)=0 for masked
          rs += p[kt][r];
        }
      rs += __shfl_xor(rs, 16, 64);
      rs += __shfl_xor(rs, 32, 64);
      if (skip) {
        l += rs;
      } else {
        l = l * alpha + rs;
#pragma unroll
        for (int dt = 0; dt < 8; ++dt)
#pragma unroll
          for (int r = 0; r < 4; ++r) o[dt][r] *= alpha;
      }

      // pack P rows into B-fragments (already in-layout, registers only)
      bf16x4 pb[4];
#pragma unroll
      for (int kt = 0; kt < 4; ++kt) {
        bf16x4 w;
        w[0] = (short)f2bf_bits(p[kt][0]); w[1] = (short)f2bf_bits(p[kt][1]);
        w[2] = (short)f2bf_bits(p[kt][2]); w[3] = (short)f2bf_bits(p[kt][3]);
        pb[kt] = w;
      }

      // O^T += V^T @ P : K=16 MFMA, A=V^T-frag (m=d, k=s), B=P (n=q, k=s)
      __builtin_amdgcn_s_setprio(1);
#pragma unroll
      for (int dt = 0; dt < 8; ++dt)
#pragma unroll
        for (int kt = 0; kt < 4; ++kt) {
          const bf16x4 vf = *(const bf16x4*)
              &vls[dt * 16 + lane16][(((kt * 4 + quad) ^ rswz)) * 4];
          o[dt] = __builtin_amdgcn_mfma_f32_16x16x16bf16_1k(vf, pb[kt], o[dt], 0, 0, 0);
        }
      __builtin_amdgcn_s_setprio(0);
    }

    const float inv_l = 1.0f / l;
    unsigned short* dst = attn + (size_t)qrow * DIM + h * HD;
#pragma unroll
    for (int dt = 0; dt < 8; ++dt) {
      u16x4 w;
#pragma unroll
      for (int r = 0; r < 4; ++r) w[r] = f2bf_bits(o[dt][r] * inv_l);
      *(u16x4*)&dst[dt * 16 + quad * 4] = w;   // 8B-aligned
    }
  }
}

// ---------------------------------------------------------------------------
extern "C" void kernel_launch(void* const* d_in, const int* in_sizes, int n_in,
                              void* d_out, int out_size, void* d_ws, size_t ws_size,
                              hipStream_t stream) {
  const float* x  = (const float*)d_in[0];
  const float* wq = (const float*)d_in[1];
  const float* wk = (const float*)d_in[2];
  const float* wv = (const float*)d_in[3];
  const float* wo = (const float*)d_in[4];
  float* out = (float*)d_out;

  unsigned short* wqkvT = (unsigned short*)d_ws;             // 6144*4096
  unsigned short* woT   = wqkvT;                             // alias (dead after GEMM1)
  unsigned short* qkv   = wqkvT + (size_t)6144 * 4096;       // 2048*6144
  unsigned short* vT    = qkv   + (size_t)2048 * 6144;       // 1024*2048
  unsigned short* attn  = vT    + (size_t)1024 * 2048;       // 2048*4096
  unsigned short* xb    = attn;                              // alias: xb dead before attn written

  const dim3 b256(256);
  transpose_f32_bf16<<<dim3(128, 128), b256, 0, stream>>>(wq, wqkvT, 4096, 4096);
  transpose_f32_bf16<<<dim3(32, 128),  b256, 0, stream>>>(wk, wqkvT + (size_t)4096 * 4096, 1024, 4096);
  transpose_f32_bf16<<<dim3(32, 128),  b256, 0, stream>>>(wv, wqkvT + (size_t)5120 * 4096, 1024, 4096);
  convert_f32_bf16<<<dim3(SEQ * DIM / 1024), b256, 0, stream>>>(x, xb);

  gemm_bt<false><<<dim3(QKV_N / BN, SEQ / BM), b256, 0, stream>>>(
      xb, DIM, wqkvT, DIM, qkv, QKV_N, DIM);

  rope_kernel<<<dim3((SEQ * 2560) / 256), b256, 0, stream>>>(qkv);

  transpose_bf16<<<dim3(32, 64), b256, 0, stream>>>(qkv + 5120, vT, 6144, 2048);

  attn_kernel<<<dim3(NQ / 2, NH), b256, 0, stream>>>(qkv, vT, attn);

  transpose_f32_bf16<<<dim3(128, 128), b256, 0, stream>>>(wo, woT, 4096, 4096);

  gemm_bt<true><<<dim3(DIM / BN, SEQ / BM), b256, 0, stream>>>(
      attn, DIM, woT, DIM, out, DIM, DIM);
}

// Round 4
// 502.477 us; speedup vs baseline: 1.2265x; 1.0755x over previous
//
#include <hip/hip_runtime.h>
#include <stdint.h>

typedef __attribute__((ext_vector_type(8))) short bf16x8;
typedef __attribute__((ext_vector_type(4))) short bf16x4;
typedef __attribute__((ext_vector_type(4))) float f32x4;
typedef __attribute__((ext_vector_type(4))) unsigned short u16x4;

#define DIM   4096
#define SEQ   2048
#define NH    32
#define NKV   8
#define HD    128
#define QKV_N 6144  /* 4096 q + 1024 k + 1024 v */
#define ATT_SCALE 0.08838834764831845f /* 1/sqrt(128) */

static __device__ __forceinline__ unsigned short f2bf_bits(float f) {
  uint32_t x = __builtin_bit_cast(uint32_t, f);
  x += 0x7fffu + ((x >> 16) & 1u);   // RNE; inputs finite
  return (unsigned short)(x >> 16);
}
static __device__ __forceinline__ float bf_bits2f(unsigned short u) {
  uint32_t x = ((uint32_t)u) << 16;
  return __builtin_bit_cast(float, x);
}

// async global->LDS, 16B per lane (global_load_lds_dwordx4).
// LDS dest must be wave-contiguous: base + lane*16.
static __device__ __forceinline__ void g2l16(const unsigned short* gp,
                                             unsigned short* lp) {
  __builtin_amdgcn_global_load_lds(
      (const __attribute__((address_space(1))) unsigned int*)gp,
      (__attribute__((address_space(3))) unsigned int*)lp, 16, 0, 0);
}

// ---------------------------------------------------------------------------
// fp32 (R x C) -> bf16 (C x R), 32x32 tiles via LDS.
// ---------------------------------------------------------------------------
__global__ __launch_bounds__(256) void transpose_f32_bf16(
    const float* __restrict__ in, unsigned short* __restrict__ out,
    int ld_in, int ld_out) {
  __shared__ unsigned short sh[32][33];
  const int c0 = blockIdx.x * 32, r0 = blockIdx.y * 32;
  const int t = threadIdx.x;
  const int cc = t & 31, rr = (t >> 5) * 4;
#pragma unroll
  for (int p = 0; p < 4; ++p)
    sh[cc][rr + p] = f2bf_bits(in[(size_t)(r0 + rr + p) * ld_in + (c0 + cc)]);
  __syncthreads();
#pragma unroll
  for (int p = 0; p < 4; ++p)
    out[(size_t)(c0 + rr + p) * ld_out + (r0 + cc)] = sh[rr + p][cc];
}

// bf16 (R x C) -> bf16 (C x R)
__global__ __launch_bounds__(256) void transpose_bf16(
    const unsigned short* __restrict__ in, unsigned short* __restrict__ out,
    int ld_in, int ld_out) {
  __shared__ unsigned short sh[32][33];
  const int c0 = blockIdx.x * 32, r0 = blockIdx.y * 32;
  const int t = threadIdx.x;
  const int cc = t & 31, rr = (t >> 5) * 4;
#pragma unroll
  for (int p = 0; p < 4; ++p)
    sh[cc][rr + p] = in[(size_t)(r0 + rr + p) * ld_in + (c0 + cc)];
  __syncthreads();
#pragma unroll
  for (int p = 0; p < 4; ++p)
    out[(size_t)(c0 + rr + p) * ld_out + (r0 + cc)] = sh[rr + p][cc];
}

// fp32 -> bf16 elementwise (x pre-conversion), 4 elems/thread
__global__ __launch_bounds__(256) void convert_f32_bf16(
    const float* __restrict__ in, unsigned short* __restrict__ out) {
  const int i = (blockIdx.x * 256 + threadIdx.x) * 4;
  const float4 v = *(const float4*)&in[i];
  u16x4 w;
  w[0] = f2bf_bits(v.x); w[1] = f2bf_bits(v.y);
  w[2] = f2bf_bits(v.z); w[3] = f2bf_bits(v.w);
  *(u16x4*)&out[i] = w;
}

// ---------------------------------------------------------------------------
// C(M,N) = A(M,K) @ Bt(N,K)^T.  bf16 in; C fp32 or bf16. 128x128, BK=64.
// m97 structure + BK=64 (half the barrier drains vs BK=32) + rule-#21
// both-sides XOR swizzle: linear LDS dest for global_load_lds, source col
// pre-swizzled (^ (row&7)<<3, permutes 16B slots within the 128B row ->
// coalescing preserved), ds_read col swizzled with the same involution.
// Accumulation order over k unchanged -> bit-identical output.
// ---------------------------------------------------------------------------
#define BM 128
#define BN 128
#define BK 64

template <bool OUT_FP32>
__global__ __launch_bounds__(256) void gemm_bt(
    const unsigned short* __restrict__ A, int lda,
    const unsigned short* __restrict__ Bt, int ldb,
    void* __restrict__ C_, int ldc, int K) {
  __shared__ __align__(16) unsigned short ldsA[BM * BK];  // 16 KB, linear
  __shared__ __align__(16) unsigned short ldsB[BN * BK];  // 16 KB, linear
  const int t = threadIdx.x;
  const int wave = t >> 6, lane = t & 63;
  const int lane16 = lane & 15, quad = lane >> 4;
  const int m0 = blockIdx.y * BM, n0 = blockIdx.x * BN;
  const int wrow = (wave >> 1) * 64, wcol = (wave & 1) * 64;

  f32x4 acc[4][4];
#pragma unroll
  for (int i = 0; i < 4; ++i)
#pragma unroll
    for (int j = 0; j < 4; ++j) acc[i][j] = (f32x4){0.f, 0.f, 0.f, 0.f};

  // staging: 4 passes/matrix; pass p, thread t -> LDS shorts p*2048 + t*8
  // (linear, wave-contiguous).  That offset corresponds to
  // row = p*32 + (t>>3), within-row slot (t&7)*8 shorts; store the
  // inverse-swizzled source element there: col = (t&7)*8 ^ ((row&7)<<3).
  const int srow = t >> 3;                              // 0..31 per pass
  const int scol = ((t & 7) * 8) ^ ((srow & 7) << 3);   // swizzled source col
  size_t arow[4], brow[4];
#pragma unroll
  for (int p = 0; p < 4; ++p) {
    arow[p] = (size_t)(m0 + p * 32 + srow) * lda + scol;
    brow[p] = (size_t)(n0 + p * 32 + srow) * ldb + scol;
  }
  const int rsw = (lane16 & 7) << 3;   // read-side swizzle (row&7 == lane16&7)

  for (int kk = 0; kk < K; kk += BK) {
    __syncthreads();
#pragma unroll
    for (int p = 0; p < 4; ++p) {
      g2l16(&A[arow[p] + kk],  &ldsA[p * 2048 + t * 8]);
      g2l16(&Bt[brow[p] + kk], &ldsB[p * 2048 + t * 8]);
    }
    __syncthreads();   // compiler drains vmcnt(0) before s_barrier

#pragma unroll
    for (int c = 0; c < 2; ++c) {   // two k-chunks of 32 per BK step
      bf16x8 af[4], bfr[4];
#pragma unroll
      for (int mi = 0; mi < 4; ++mi)
        af[mi] = *(const bf16x8*)
            &ldsA[(wrow + mi * 16 + lane16) * BK + ((c * 32 + quad * 8) ^ rsw)];
#pragma unroll
      for (int ni = 0; ni < 4; ++ni)
        bfr[ni] = *(const bf16x8*)
            &ldsB[(wcol + ni * 16 + lane16) * BK + ((c * 32 + quad * 8) ^ rsw)];
#pragma unroll
      for (int mi = 0; mi < 4; ++mi)
#pragma unroll
        for (int ni = 0; ni < 4; ++ni)
          acc[mi][ni] = __builtin_amdgcn_mfma_f32_16x16x32_bf16(
              af[mi], bfr[ni], acc[mi][ni], 0, 0, 0);
    }
  }

#pragma unroll
  for (int mi = 0; mi < 4; ++mi)
#pragma unroll
    for (int ni = 0; ni < 4; ++ni)
#pragma unroll
      for (int r = 0; r < 4; ++r) {
        const int row = m0 + wrow + mi * 16 + quad * 4 + r;
        const int col = n0 + wcol + ni * 16 + lane16;
        if (OUT_FP32)
          ((float*)C_)[(size_t)row * ldc + col] = acc[mi][ni][r];
        else
          ((unsigned short*)C_)[(size_t)row * ldc + col] = f2bf_bits(acc[mi][ni][r]);
      }
}

// ---------------------------------------------------------------------------
// Interleaved RoPE in place on qkv.
// ---------------------------------------------------------------------------
__global__ __launch_bounds__(256) void rope_kernel(unsigned short* __restrict__ qkv) {
  const int idx = blockIdx.x * 256 + threadIdx.x;
  const int pos = idx / 2560;
  const int rem = idx - pos * 2560;
  const int head = rem >> 6;
  const int i = rem & 63;
  const float inv_freq = __expf(-(float)(2 * i) * (9.210340371976184f / 128.0f));
  const float ang = (float)pos * inv_freq;
  float s, c;
  __sincosf(ang, &s, &c);
  const int col = (head < 32) ? head * 128 + 2 * i
                              : 4096 + (head - 32) * 128 + 2 * i;
  unsigned short* p = qkv + (size_t)pos * QKV_N + col;
  const float tr = bf_bits2f(p[0]), ti = bf_bits2f(p[1]);
  p[0] = f2bf_bits(tr * c - ti * s);
  p[1] = f2bf_bits(tr * s + ti * c);
}

// ---------------------------------------------------------------------------
// Flash attention, operand-swapped (S^T = K@Q^T; PV via K=16 MFMA).
// Causal-pairing load balance: block b -> q-tiles {31-b, b} = 33 iters each.
// T14 async-STAGE (reg prefetch across raw barrier), V 8B-unit XOR swizzle,
// T13 defer-max, T5 setprio.  (Verified correct in round 3.)
// ---------------------------------------------------------------------------
#define QT 64
#define KT 64
#define KLS (HD + 8)   /* 136 shorts, 272 B rows: balanced banks for b128 reads */
#define NQ  (SEQ / QT) /* 32 q-tiles */
#define DEFER_THR 8.0f

__global__ __launch_bounds__(256) void attn_kernel(
    const unsigned short* __restrict__ qkv,
    const unsigned short* __restrict__ vT,
    unsigned short* __restrict__ attn) {
  __shared__ __align__(16) unsigned short kls[KT][KLS];   // 17408 B
  __shared__ __align__(16) unsigned short vls[HD][KT];    // 16384 B, swizzled

  const int t = threadIdx.x;
  const int wave = t >> 6, lane = t & 63;
  const int lane16 = lane & 15, quad = lane >> 4;
  const int h = blockIdx.y, kvh = h >> 2;
  const unsigned short* kbase = qkv + 4096 + kvh * HD;
  const unsigned short* vbase = vT + (size_t)kvh * HD * SEQ;

  // staging geometry (fixed per thread)
  const int kr = t >> 2, kc = (t & 3) * 8;   // K tile: row, col base
  const int vd = t >> 1;                     // V^T dim row
  const int vu0 = (t & 1) * 8;               // V 8B-unit base (1 unit = 4 shorts)
  const int vswz = (vd & 7) << 1;            // XOR mask on 8B units (write side)
  const int rswz = (lane16 & 7) << 1;        // XOR mask on 8B units (read side)
  const unsigned short* ksrc0 = &kbase[(size_t)kr * QKV_N + kc];
  const unsigned short* vsrc0 = &vbase[(size_t)vd * SEQ + (t & 1) * 32];

  bf16x8 kreg[4], vreg[4];

  for (int half = 0; half < 2; ++half) {
    const int qt = half ? (int)blockIdx.x : (NQ - 1 - (int)blockIdx.x);
    const int q0 = qt * QT;
    const int wq0 = q0 + wave * 16;
    const int qrow = wq0 + lane16;                 // this lane's q row
    const int nkb = qt + 1;

    // prologue prefetch of tile kb=0 (registers only; LDS still owned by
    // previous half's compute until the first __syncthreads below)
#pragma unroll
    for (int j = 0; j < 4; ++j) kreg[j] = *(const bf16x8*)&ksrc0[j * 32];
#pragma unroll
    for (int j = 0; j < 4; ++j) vreg[j] = *(const bf16x8*)&vsrc0[j * 8];

    const unsigned short* qbase = qkv + (size_t)wq0 * QKV_N + h * HD;

    // Q fragments (B-operand): B[n=lane16][k=quad*8+j]
    bf16x8 qf[4];
#pragma unroll
    for (int dc = 0; dc < 4; ++dc)
      qf[dc] = *(const bf16x8*)&qbase[(size_t)lane16 * QKV_N + dc * 32 + quad * 8];

    f32x4 o[8];  // O^T[d][q] accumulators, d = dt*16 + (quad*4+reg)
#pragma unroll
    for (int i = 0; i < 8; ++i) o[i] = (f32x4){0.f, 0.f, 0.f, 0.f};
    float m = -INFINITY, l = 0.f;

    for (int kb = 0; kb < nkb; ++kb) {
      const int key0 = kb * KT;
      __syncthreads();   // all waves done reading LDS; drains prefetch vmcnt

      // store staged tile regs -> LDS
#pragma unroll
      for (int j = 0; j < 4; ++j)
        *(bf16x8*)&kls[kr][kc + j * 32] = kreg[j];
#pragma unroll
      for (int j = 0; j < 4; ++j)
        *(bf16x8*)&vls[vd][((vu0 + j * 2) ^ vswz) * 4] = vreg[j];

      // prefetch next tile (stays in flight across the raw barrier below)
      if (kb + 1 < nkb) {
        const unsigned short* ks = ksrc0 + (size_t)(kb + 1) * KT * QKV_N;
        const unsigned short* vs = vsrc0 + (kb + 1) * KT;
#pragma unroll
        for (int j = 0; j < 4; ++j) kreg[j] = *(const bf16x8*)&ks[j * 32];
#pragma unroll
        for (int j = 0; j < 4; ++j) vreg[j] = *(const bf16x8*)&vs[j * 8];
      }

      asm volatile("s_waitcnt lgkmcnt(0)" ::: "memory");  // ds_writes visible
      __builtin_amdgcn_s_barrier();                       // no vmcnt drain

      // S^T[s][q]: A=K (m=s), B=Q (n=q); 4 key sub-tiles
      f32x4 S[4];
      __builtin_amdgcn_s_setprio(1);
#pragma unroll
      for (int kt = 0; kt < 4; ++kt) {
        f32x4 sacc = (f32x4){0.f, 0.f, 0.f, 0.f};
#pragma unroll
        for (int dc = 0; dc < 4; ++dc) {
          const bf16x8 kf = *(const bf16x8*)&kls[kt * 16 + lane16][dc * 32 + quad * 8];
          sacc = __builtin_amdgcn_mfma_f32_16x16x32_bf16(kf, qf[dc], sacc, 0, 0, 0);
        }
        S[kt] = sacc;
      }
      __builtin_amdgcn_s_setprio(0);

      // per-lane softmax over this lane's 16 s-values, reduce across quads
      float sv[4][4], mx = -INFINITY;
#pragma unroll
      for (int kt = 0; kt < 4; ++kt)
#pragma unroll
        for (int r = 0; r < 4; ++r) {
          const int key = key0 + kt * 16 + quad * 4 + r;
          sv[kt][r] = (key <= qrow) ? S[kt][r] * ATT_SCALE : -INFINITY;
          mx = fmaxf(mx, sv[kt][r]);
        }
      mx = fmaxf(mx, __shfl_xor(mx, 16, 64));
      mx = fmaxf(mx, __shfl_xor(mx, 32, 64));

      // T13 defer-max: keep old m while growth <= THR (p bounded by e^THR)
      const bool skip = __all(mx <= m + DEFER_THR);
      float alpha = 1.f;
      if (!skip) {
        const float newm = fmaxf(m, mx);
        alpha = __expf(m - newm);   // 0 on first block
        m = newm;
      }
      float p[4][4], rs = 0.f;
#pragma unroll
      for (int kt = 0; kt < 4; ++kt)
#pragma unroll
        for (int r = 0; r < 4; ++r) {
          p[kt][r] = __expf(sv[kt][r] - m);  // exp(-inf)=0 for masked
          rs += p[kt][r];
        }
      rs += __shfl_xor(rs, 16, 64);
      rs += __shfl_xor(rs, 32, 64);
      if (skip) {
        l += rs;
      } else {
        l = l * alpha + rs;
#pragma unroll
        for (int dt = 0; dt < 8; ++dt)
#pragma unroll
          for (int r = 0; r < 4; ++r) o[dt][r] *= alpha;
      }

      // pack P rows into B-fragments (already in-layout, registers only)
      bf16x4 pb[4];
#pragma unroll
      for (int kt = 0; kt < 4; ++kt) {
        bf16x4 w;
        w[0] = (short)f2bf_bits(p[kt][0]); w[1] = (short)f2bf_bits(p[kt][1]);
        w[2] = (short)f2bf_bits(p[kt][2]); w[3] = (short)f2bf_bits(p[kt][3]);
        pb[kt] = w;
      }

      // O^T += V^T @ P : K=16 MFMA, A=V^T-frag (m=d, k=s), B=P (n=q, k=s)
      __builtin_amdgcn_s_setprio(1);
#pragma unroll
      for (int dt = 0; dt < 8; ++dt)
#pragma unroll
        for (int kt = 0; kt < 4; ++kt) {
          const bf16x4 vf = *(const bf16x4*)
              &vls[dt * 16 + lane16][(((kt * 4 + quad) ^ rswz)) * 4];
          o[dt] = __builtin_amdgcn_mfma_f32_16x16x16bf16_1k(vf, pb[kt], o[dt], 0, 0, 0);
        }
      __builtin_amdgcn_s_setprio(0);
    }

    const float inv_l = 1.0f / l;
    unsigned short* dst = attn + (size_t)qrow * DIM + h * HD;
#pragma unroll
    for (int dt = 0; dt < 8; ++dt) {
      u16x4 w;
#pragma unroll
      for (int r = 0; r < 4; ++r) w[r] = f2bf_bits(o[dt][r] * inv_l);
      *(u16x4*)&dst[dt * 16 + quad * 4] = w;   // 8B-aligned
    }
  }
}

// ---------------------------------------------------------------------------
extern "C" void kernel_launch(void* const* d_in, const int* in_sizes, int n_in,
                              void* d_out, int out_size, void* d_ws, size_t ws_size,
                              hipStream_t stream) {
  const float* x  = (const float*)d_in[0];
  const float* wq = (const float*)d_in[1];
  const float* wk = (const float*)d_in[2];
  const float* wv = (const float*)d_in[3];
  const float* wo = (const float*)d_in[4];
  float* out = (float*)d_out;

  unsigned short* wqkvT = (unsigned short*)d_ws;             // 6144*4096
  unsigned short* woT   = wqkvT;                             // alias (dead after GEMM1)
  unsigned short* qkv   = wqkvT + (size_t)6144 * 4096;       // 2048*6144
  unsigned short* vT    = qkv   + (size_t)2048 * 6144;       // 1024*2048
  unsigned short* attn  = vT    + (size_t)1024 * 2048;       // 2048*4096
  unsigned short* xb    = attn;                              // alias: xb dead before attn written

  const dim3 b256(256);
  transpose_f32_bf16<<<dim3(128, 128), b256, 0, stream>>>(wq, wqkvT, 4096, 4096);
  transpose_f32_bf16<<<dim3(32, 128),  b256, 0, stream>>>(wk, wqkvT + (size_t)4096 * 4096, 1024, 4096);
  transpose_f32_bf16<<<dim3(32, 128),  b256, 0, stream>>>(wv, wqkvT + (size_t)5120 * 4096, 1024, 4096);
  convert_f32_bf16<<<dim3(SEQ * DIM / 1024), b256, 0, stream>>>(x, xb);

  gemm_bt<false><<<dim3(QKV_N / BN, SEQ / BM), b256, 0, stream>>>(
      xb, DIM, wqkvT, DIM, qkv, QKV_N, DIM);

  rope_kernel<<<dim3((SEQ * 2560) / 256), b256, 0, stream>>>(qkv);

  transpose_bf16<<<dim3(32, 64), b256, 0, stream>>>(qkv + 5120, vT, 6144, 2048);

  attn_kernel<<<dim3(NQ / 2, NH), b256, 0, stream>>>(qkv, vT, attn);

  transpose_f32_bf16<<<dim3(128, 128), b256, 0, stream>>>(wo, woT, 4096, 4096);

  gemm_bt<true><<<dim3(DIM / BN, SEQ / BM), b256, 0, stream>>>(
      attn, DIM, woT, DIM, out, DIM, DIM);
}